// Round 1
// baseline (434.997 us; speedup 1.0000x reference)
//
#include <hip/hip_runtime.h>
#include <math.h>

#define N_NODES 100000
#define N_EDGES 6400000
#define LOG2_10 3.321928094887362f

// Edge kernel: syn[dst[e]] += rates[src[e]] * weights[e]
// 4 edges per thread, vectorized loads.
__global__ void edge_scatter_kernel(const float* __restrict__ rates,
                                    const float* __restrict__ weights,
                                    const int* __restrict__ src,
                                    const int* __restrict__ dst,
                                    float* __restrict__ syn) {
    int i = blockIdx.x * blockDim.x + threadIdx.x;
    int e = i * 4;
    if (e + 3 < N_EDGES) {
        int4   s = *reinterpret_cast<const int4*>(src + e);
        int4   d = *reinterpret_cast<const int4*>(dst + e);
        float4 w = *reinterpret_cast<const float4*>(weights + e);
        atomicAdd(&syn[d.x], rates[s.x] * w.x);
        atomicAdd(&syn[d.y], rates[s.y] * w.y);
        atomicAdd(&syn[d.z], rates[s.z] * w.z);
        atomicAdd(&syn[d.w], rates[s.w] * w.w);
    } else {
        for (; e < N_EDGES; ++e) {
            atomicAdd(&syn[dst[e]], rates[src[e]] * weights[e]);
        }
    }
}

// Node epilogue: out[v] = (-r + 10^gain * tanh((is_input ? ext : syn) + baseline)) / tau
__global__ void node_kernel(const float* __restrict__ rates,
                            const float* __restrict__ gain,
                            const float* __restrict__ time_constant,
                            const float* __restrict__ baseline,
                            const float* __restrict__ ext_input,
                            const int*   __restrict__ is_input,
                            const float* __restrict__ syn,
                            float* __restrict__ out) {
    int v = blockIdx.x * blockDim.x + threadIdx.x;
    if (v >= N_NODES) return;
    float total = (is_input[v] != 0 ? ext_input[v] : syn[v]) + baseline[v];
    float act = tanhf(total);
    float g = exp2f(gain[v] * LOG2_10);   // 10^gain
    out[v] = (-rates[v] + g * act) / time_constant[v];
}

extern "C" void kernel_launch(void* const* d_in, const int* in_sizes, int n_in,
                              void* d_out, int out_size, void* d_ws, size_t ws_size,
                              hipStream_t stream) {
    const float* rates         = (const float*)d_in[0];
    const float* weights       = (const float*)d_in[1];
    const float* gain          = (const float*)d_in[2];
    const float* time_constant = (const float*)d_in[3];
    const float* baseline      = (const float*)d_in[4];
    const float* ext_input     = (const float*)d_in[5];
    const int*   src           = (const int*)d_in[6];
    const int*   dst           = (const int*)d_in[7];
    const int*   is_input      = (const int*)d_in[8];
    float* out = (float*)d_out;

    float* syn = (float*)d_ws;  // N_NODES floats of scratch

    // Zero the accumulator (d_ws is poisoned to 0xAA before every launch).
    hipMemsetAsync(syn, 0, N_NODES * sizeof(float), stream);

    // Edge scatter: 4 edges/thread.
    int threads_e = (N_EDGES + 3) / 4;
    int block = 256;
    int grid_e = (threads_e + block - 1) / block;
    edge_scatter_kernel<<<grid_e, block, 0, stream>>>(rates, weights, src, dst, syn);

    // Node epilogue.
    int grid_n = (N_NODES + block - 1) / block;
    node_kernel<<<grid_n, block, 0, stream>>>(rates, gain, time_constant, baseline,
                                              ext_input, is_input, syn, out);
}

// Round 2
// 416.239 us; speedup vs baseline: 1.0451x; 1.0451x over previous
//
#include <hip/hip_runtime.h>
#include <math.h>

#define N_NODES 100000
#define N_EDGES 6400000
#define N_XCD   8
#define LOG2_10 3.321928094887362f

// Read the hardware XCD id (0..7 on MI355X). All waves observing the same
// value share one (non-cross-coherent) L2 — so workgroup-scope atomics to a
// per-XCD private buffer execute in that shared L2 and are mutually atomic.
__device__ __forceinline__ int xcc_id() {
    int x;
    asm volatile("s_getreg_b32 %0, hwreg(HW_REG_XCC_ID)" : "=s"(x));
    return x & (N_XCD - 1);
}

// Edge kernel: syn_k[dst[e]] += rates[src[e]] * weights[e], k = this XCD.
// Workgroup-scope atomic => executes at the local XCD L2 (no memory-side
// round trip). 4 edges per thread, vectorized loads.
__global__ void edge_scatter_kernel(const float* __restrict__ rates,
                                    const float* __restrict__ weights,
                                    const int* __restrict__ src,
                                    const int* __restrict__ dst,
                                    float* __restrict__ syn) {
    float* mysyn = syn + (size_t)xcc_id() * N_NODES;
    int i = blockIdx.x * blockDim.x + threadIdx.x;
    int e = i * 4;
    if (e + 3 < N_EDGES) {
        int4   s = *reinterpret_cast<const int4*>(src + e);
        int4   d = *reinterpret_cast<const int4*>(dst + e);
        float4 w = *reinterpret_cast<const float4*>(weights + e);
        __hip_atomic_fetch_add(&mysyn[d.x], rates[s.x] * w.x, __ATOMIC_RELAXED, __HIP_MEMORY_SCOPE_WORKGROUP);
        __hip_atomic_fetch_add(&mysyn[d.y], rates[s.y] * w.y, __ATOMIC_RELAXED, __HIP_MEMORY_SCOPE_WORKGROUP);
        __hip_atomic_fetch_add(&mysyn[d.z], rates[s.z] * w.z, __ATOMIC_RELAXED, __HIP_MEMORY_SCOPE_WORKGROUP);
        __hip_atomic_fetch_add(&mysyn[d.w], rates[s.w] * w.w, __ATOMIC_RELAXED, __HIP_MEMORY_SCOPE_WORKGROUP);
    } else {
        for (; e < N_EDGES; ++e) {
            __hip_atomic_fetch_add(&mysyn[dst[e]], rates[src[e]] * weights[e], __ATOMIC_RELAXED, __HIP_MEMORY_SCOPE_WORKGROUP);
        }
    }
}

// Node epilogue: sum the 8 per-XCD copies, then
// out[v] = (-r + 10^gain * tanh((is_input ? ext : syn) + baseline)) / tau
__global__ void node_kernel(const float* __restrict__ rates,
                            const float* __restrict__ gain,
                            const float* __restrict__ time_constant,
                            const float* __restrict__ baseline,
                            const float* __restrict__ ext_input,
                            const int*   __restrict__ is_input,
                            const float* __restrict__ syn,
                            float* __restrict__ out) {
    int v = blockIdx.x * blockDim.x + threadIdx.x;
    if (v >= N_NODES) return;
    float s = 0.0f;
    #pragma unroll
    for (int k = 0; k < N_XCD; ++k) s += syn[(size_t)k * N_NODES + v];
    float total = (is_input[v] != 0 ? ext_input[v] : s) + baseline[v];
    float act = tanhf(total);
    float g = exp2f(gain[v] * LOG2_10);   // 10^gain
    out[v] = (-rates[v] + g * act) / time_constant[v];
}

extern "C" void kernel_launch(void* const* d_in, const int* in_sizes, int n_in,
                              void* d_out, int out_size, void* d_ws, size_t ws_size,
                              hipStream_t stream) {
    const float* rates         = (const float*)d_in[0];
    const float* weights       = (const float*)d_in[1];
    const float* gain          = (const float*)d_in[2];
    const float* time_constant = (const float*)d_in[3];
    const float* baseline      = (const float*)d_in[4];
    const float* ext_input     = (const float*)d_in[5];
    const int*   src           = (const int*)d_in[6];
    const int*   dst           = (const int*)d_in[7];
    const int*   is_input      = (const int*)d_in[8];
    float* out = (float*)d_out;

    float* syn = (float*)d_ws;  // N_XCD * N_NODES floats of scratch

    // Zero the accumulators (d_ws is poisoned to 0xAA before every launch).
    hipMemsetAsync(syn, 0, (size_t)N_XCD * N_NODES * sizeof(float), stream);

    // Edge scatter: 4 edges/thread.
    int threads_e = (N_EDGES + 3) / 4;
    int block = 256;
    int grid_e = (threads_e + block - 1) / block;
    edge_scatter_kernel<<<grid_e, block, 0, stream>>>(rates, weights, src, dst, syn);

    // Node epilogue.
    int grid_n = (N_NODES + block - 1) / block;
    node_kernel<<<grid_n, block, 0, stream>>>(rates, gain, time_constant, baseline,
                                              ext_input, is_input, syn, out);
}

// Round 3
// 213.555 us; speedup vs baseline: 2.0369x; 1.9491x over previous
//
#include <hip/hip_runtime.h>
#include <math.h>

#define N_NODES 100000
#define N_EDGES 6400000
#define K_BINS  8
#define BIN_SZ  12500          // N_NODES / K_BINS exactly
#define BLOCK   1024
#define LOG2_10 3.321928094887362f

// Each block owns (bin b, edge-chunk c). It scans chunk c's edges with fully
// coalesced vector loads, LDS-atomic-adds the edges landing in bin b, then
// flushes its 12.5k-float bin to a per-chunk private copy with plain stores.
// No global atomics anywhere.
__global__ __launch_bounds__(BLOCK) void edge_bin_kernel(
        const float* __restrict__ rates,
        const float* __restrict__ weights,
        const int* __restrict__ src,
        const int* __restrict__ dst,
        float* __restrict__ part,      // [n_chunks][N_NODES]
        int n_chunks, int edges_per_chunk) {
    __shared__ float bin[BIN_SZ];      // 50 KB -> 2 blocks/CU at block=1024
    const int b = blockIdx.x % K_BINS; // adjacent blocks share the edge chunk
    const int c = blockIdx.x / K_BINS;
    const int base_node = b * BIN_SZ;

    for (int i = threadIdx.x; i < BIN_SZ; i += BLOCK) bin[i] = 0.0f;
    __syncthreads();

    const long e0 = (long)c * edges_per_chunk;
    const int nvec = edges_per_chunk >> 2;            // divisible by 4
    const int4*   s4 = (const int4*)(src + e0);
    const int4*   d4 = (const int4*)(dst + e0);
    const float4* w4 = (const float4*)(weights + e0);

    for (int i = threadIdx.x; i < nvec; i += BLOCK) {
        int4   d = d4[i];
        int4   s = s4[i];
        float4 w = w4[i];
        unsigned dx = (unsigned)(d.x - base_node);
        unsigned dy = (unsigned)(d.y - base_node);
        unsigned dz = (unsigned)(d.z - base_node);
        unsigned dw = (unsigned)(d.w - base_node);
        // rates[] gather predicated under the bin match: only 1/8 of lanes load
        if (dx < BIN_SZ) atomicAdd(&bin[dx], rates[s.x] * w.x);
        if (dy < BIN_SZ) atomicAdd(&bin[dy], rates[s.y] * w.y);
        if (dz < BIN_SZ) atomicAdd(&bin[dz], rates[s.z] * w.z);
        if (dw < BIN_SZ) atomicAdd(&bin[dw], rates[s.w] * w.w);
    }
    __syncthreads();

    float* outp = part + (size_t)c * N_NODES + base_node;
    for (int i = threadIdx.x; i < BIN_SZ; i += BLOCK) outp[i] = bin[i];
}

// Node epilogue: sum the n_chunks copies, then
// out[v] = (-r + 10^gain * tanh((is_input ? ext : syn) + baseline)) / tau
__global__ void node_kernel(const float* __restrict__ rates,
                            const float* __restrict__ gain,
                            const float* __restrict__ time_constant,
                            const float* __restrict__ baseline,
                            const float* __restrict__ ext_input,
                            const int*   __restrict__ is_input,
                            const float* __restrict__ part,
                            float* __restrict__ out,
                            int n_chunks) {
    int v = blockIdx.x * blockDim.x + threadIdx.x;
    if (v >= N_NODES) return;
    float s = 0.0f;
    for (int k = 0; k < n_chunks; ++k) s += part[(size_t)k * N_NODES + v];
    float total = (is_input[v] != 0 ? ext_input[v] : s) + baseline[v];
    float act = tanhf(total);
    float g = exp2f(gain[v] * LOG2_10);   // 10^gain
    out[v] = (-rates[v] + g * act) / time_constant[v];
}

extern "C" void kernel_launch(void* const* d_in, const int* in_sizes, int n_in,
                              void* d_out, int out_size, void* d_ws, size_t ws_size,
                              hipStream_t stream) {
    const float* rates         = (const float*)d_in[0];
    const float* weights       = (const float*)d_in[1];
    const float* gain          = (const float*)d_in[2];
    const float* time_constant = (const float*)d_in[3];
    const float* baseline      = (const float*)d_in[4];
    const float* ext_input     = (const float*)d_in[5];
    const int*   src           = (const int*)d_in[6];
    const int*   dst           = (const int*)d_in[7];
    const int*   is_input      = (const int*)d_in[8];
    float* out  = (float*)d_out;
    float* part = (float*)d_ws;

    // Pick the largest power-of-two chunk count that fits in d_ws (64 ideal:
    // 512 blocks = 2/CU; every copy is fully overwritten, so no memset needed).
    int n_chunks = 64;
    while (n_chunks > 1 && (size_t)n_chunks * N_NODES * sizeof(float) > ws_size)
        n_chunks >>= 1;
    int edges_per_chunk = N_EDGES / n_chunks;   // 6.4M / 2^k: divisible by 4

    int grid_e = K_BINS * n_chunks;
    edge_bin_kernel<<<grid_e, BLOCK, 0, stream>>>(rates, weights, src, dst,
                                                  part, n_chunks, edges_per_chunk);

    int block = 256;
    int grid_n = (N_NODES + block - 1) / block;
    node_kernel<<<grid_n, block, 0, stream>>>(rates, gain, time_constant, baseline,
                                              ext_input, is_input, part, out, n_chunks);
}

// Round 4
// 187.664 us; speedup vs baseline: 2.3180x; 1.1380x over previous
//
#include <hip/hip_runtime.h>
#include <math.h>

#define N_NODES 100000
#define N_EDGES 6400000
#define K_BINS  5
#define BIN_SZ  20000          // N_NODES / K_BINS exactly; 80,000 B LDS -> 2 blocks/CU
#define BLOCK   1024
#define LOG2_10 3.321928094887362f

// Each block owns (bin b, edge-chunk c). It scans chunk c's edges with fully
// coalesced vector loads, LDS-atomic-adds the edges landing in bin b, then
// flushes its 20k-float bin to a per-chunk private copy with float4 stores.
// No global atomics anywhere. K=5 bins of 80KB LDS => 2 blocks/CU, full
// occupancy, and only a 5x edge re-scan (vs 8x with 50KB bins).
__global__ __launch_bounds__(BLOCK) void edge_bin_kernel(
        const float* __restrict__ rates,
        const float* __restrict__ weights,
        const int* __restrict__ src,
        const int* __restrict__ dst,
        float* __restrict__ part,      // [n_chunks][N_NODES]
        int n_chunks, int edges_per_chunk) {
    __shared__ float bin[BIN_SZ];
    const int b = blockIdx.x % K_BINS; // adjacent blocks share the edge chunk
    const int c = blockIdx.x / K_BINS;
    const int base_node = b * BIN_SZ;

    for (int i = threadIdx.x; i < BIN_SZ; i += BLOCK) bin[i] = 0.0f;
    __syncthreads();

    const long e0 = (long)c * edges_per_chunk;
    const int nvec = edges_per_chunk >> 2;            // divisible by 4
    const int4*   s4 = (const int4*)(src + e0);
    const int4*   d4 = (const int4*)(dst + e0);
    const float4* w4 = (const float4*)(weights + e0);

    for (int i = threadIdx.x; i < nvec; i += BLOCK) {
        int4   d = d4[i];
        int4   s = s4[i];
        float4 w = w4[i];
        unsigned dx = (unsigned)(d.x - base_node);
        unsigned dy = (unsigned)(d.y - base_node);
        unsigned dz = (unsigned)(d.z - base_node);
        unsigned dw = (unsigned)(d.w - base_node);
        // rates[] gather predicated under the bin match: only 1/5 of lanes load
        if (dx < BIN_SZ) atomicAdd(&bin[dx], rates[s.x] * w.x);
        if (dy < BIN_SZ) atomicAdd(&bin[dy], rates[s.y] * w.y);
        if (dz < BIN_SZ) atomicAdd(&bin[dz], rates[s.z] * w.z);
        if (dw < BIN_SZ) atomicAdd(&bin[dw], rates[s.w] * w.w);
    }
    __syncthreads();

    // Vectorized flush: 20000 floats = 5000 float4s.
    float4* outp = (float4*)(part + (size_t)c * N_NODES + base_node);
    for (int i = threadIdx.x; i < (BIN_SZ >> 2); i += BLOCK) {
        outp[i] = make_float4(bin[4*i], bin[4*i+1], bin[4*i+2], bin[4*i+3]);
    }
}

// Node epilogue: sum the n_chunks copies, then
// out[v] = (-r + 10^gain * tanh((is_input ? ext : syn) + baseline)) / tau
__global__ void node_kernel(const float* __restrict__ rates,
                            const float* __restrict__ gain,
                            const float* __restrict__ time_constant,
                            const float* __restrict__ baseline,
                            const float* __restrict__ ext_input,
                            const int*   __restrict__ is_input,
                            const float* __restrict__ part,
                            float* __restrict__ out,
                            int n_chunks) {
    int v = blockIdx.x * blockDim.x + threadIdx.x;
    if (v >= N_NODES) return;
    float s0 = 0.0f, s1 = 0.0f, s2 = 0.0f, s3 = 0.0f;
    int k = 0;
    for (; k + 3 < n_chunks; k += 4) {
        s0 += part[(size_t)(k + 0) * N_NODES + v];
        s1 += part[(size_t)(k + 1) * N_NODES + v];
        s2 += part[(size_t)(k + 2) * N_NODES + v];
        s3 += part[(size_t)(k + 3) * N_NODES + v];
    }
    for (; k < n_chunks; ++k) s0 += part[(size_t)k * N_NODES + v];
    float s = (s0 + s1) + (s2 + s3);
    float total = (is_input[v] != 0 ? ext_input[v] : s) + baseline[v];
    float act = tanhf(total);
    float g = exp2f(gain[v] * LOG2_10);   // 10^gain
    out[v] = (-rates[v] + g * act) / time_constant[v];
}

extern "C" void kernel_launch(void* const* d_in, const int* in_sizes, int n_in,
                              void* d_out, int out_size, void* d_ws, size_t ws_size,
                              hipStream_t stream) {
    const float* rates         = (const float*)d_in[0];
    const float* weights       = (const float*)d_in[1];
    const float* gain          = (const float*)d_in[2];
    const float* time_constant = (const float*)d_in[3];
    const float* baseline      = (const float*)d_in[4];
    const float* ext_input     = (const float*)d_in[5];
    const int*   src           = (const int*)d_in[6];
    const int*   dst           = (const int*)d_in[7];
    const int*   is_input      = (const int*)d_in[8];
    float* out  = (float*)d_out;
    float* part = (float*)d_ws;

    // Largest chunk count (from the preference list) whose partials fit d_ws.
    // 100 chunks -> 500 blocks ~= the 512-block residency capacity (2/CU).
    // All candidates divide N_EDGES with edges_per_chunk % 4 == 0.
    static const int cand[] = {100, 50, 25, 20, 10, 5, 4, 2, 1};
    int n_chunks = 1;
    for (int i = 0; i < (int)(sizeof(cand)/sizeof(cand[0])); ++i) {
        if ((size_t)cand[i] * N_NODES * sizeof(float) <= ws_size) { n_chunks = cand[i]; break; }
    }
    int edges_per_chunk = N_EDGES / n_chunks;

    int grid_e = K_BINS * n_chunks;
    edge_bin_kernel<<<grid_e, BLOCK, 0, stream>>>(rates, weights, src, dst,
                                                  part, n_chunks, edges_per_chunk);

    int block = 256;
    int grid_n = (N_NODES + block - 1) / block;
    node_kernel<<<grid_n, block, 0, stream>>>(rates, gain, time_constant, baseline,
                                              ext_input, is_input, part, out, n_chunks);
}